// Round 11
// baseline (9456.918 us; speedup 1.0000x reference)
//
#include <hip/hip_runtime.h>
#include <hip/hip_bf16.h>

typedef float f32x4 __attribute__((ext_vector_type(4)));
typedef short short8v __attribute__((ext_vector_type(8)));
typedef unsigned int uint;

constexpr int TSTEPS = 512;

union FragU { uint u[4]; short8v v; };

__device__ __forceinline__ float silu_f(float x) {
    return __fdividef(x, 1.0f + __expf(-x));
}
__device__ __forceinline__ f32x4 silu4(f32x4 v) {
    f32x4 r;
    r.x = silu_f(v.x); r.y = silu_f(v.y);
    r.z = silu_f(v.z); r.w = silu_f(v.w);
    return r;
}

// ---- setup-path split (RNE, bf16 pattern in top 16 bits) ----
__device__ __forceinline__ uint bf16_rne(float x) {
    uint ux = __float_as_uint(x);
    return (ux + 0x7FFFu + ((ux >> 16) & 1u)) & 0xFFFF0000u;
}
__device__ __forceinline__ void split2u(float x, uint &h, uint &l) {
    h = bf16_rne(x);
    float rem = x - __uint_as_float(h);
    l = bf16_rne(rem);
}
// ---- hot-path split via v_cvt_pk_bf16_f32 (bit-identical to split2u) ----
__device__ __forceinline__ uint cvtpk(float a, float b) {
    union { __hip_bfloat162 h; uint u; } cv;
    cv.h = __float22bfloat162_rn(make_float2(a, b));
    return cv.u;
}
__device__ __forceinline__ void split4_pk(const f32x4 v, uint2 &hi, uint2 &lo) {
    hi.x = cvtpk(v.x, v.y);
    hi.y = cvtpk(v.z, v.w);
    float h0 = __uint_as_float(hi.x << 16);
    float h1 = __uint_as_float(hi.x & 0xFFFF0000u);
    float h2 = __uint_as_float(hi.y << 16);
    float h3 = __uint_as_float(hi.y & 0xFFFF0000u);
    lo.x = cvtpk(v.x - h0, v.y - h1);
    lo.y = cvtpk(v.z - h2, v.w - h3);
}

#define MFMA16(A, B, C) __builtin_amdgcn_mfma_f32_16x16x32_bf16((A), (B), (C), 0, 0, 0)

// LDS index in shorts: [lev][pair(16)][b(16)][8 shorts]; feature j = 8*pair + e
#define SXI(lev, p, bb) ((((lev)*16 + (p))*16 + (bb))*8)

// ONE 64-lane wave per block, 16 batch rows, ZERO barriers.
// The wave owns the full MLP: W2 2-level split in 256 VGPRs (8 jt x 4 kt x 2 lev
// A-frags), W1 (bias folded into spare g3 k-slots, exact 2-level), W3^T for an
// MFMA-based layer 3. Feature redistribution (C-layout -> B-layout) is an
// IN-WAVE LDS transpose: program-order ds_write -> lgkmcnt -> ds_read; no
// __syncthreads in the hot loop at all. 16x16x32 layouts (m89-verified):
//   A: row=lane&15, k=8*(lane>>4)+e ; B: col=lane&15, k=8*(lane>>4)+e
//   C/D: col=lane&15, row=4*(lane>>4)+reg
__global__ __launch_bounds__(64, 1)
void odernn_v11(const float* __restrict__ quat,
                const float* __restrict__ W1, const float* __restrict__ b1,
                const float* __restrict__ W2, const float* __restrict__ b2,
                const float* __restrict__ W3, const float* __restrict__ b3,
                float* __restrict__ out)
{
    __shared__ short sx1[2 * 16 * 16 * 8];   // 8 KB x1 (2-level bf16)
    __shared__ short sx2[2 * 16 * 16 * 8];   // 8 KB x2
    __shared__ float sb2s[128];
    __shared__ float sck[64];                // L3 output broadcast

    const int tid = threadIdx.x;
    const int b   = tid & 15;    // batch col / A-row
    const int g   = tid >> 4;    // k-subgroup
    const int rowbase = blockIdx.x * 16;

    sb2s[tid]      = b2[tid];
    sb2s[tid + 64] = b2[tid + 64];

    // ---- W2^T full, 2-level: A2[jt][kt][lev], j = 16jt + b, k = 32kt + 8g + e ----
    short8v A2[8][4][2];
#pragma unroll
    for (int jt = 0; jt < 8; ++jt)
#pragma unroll
        for (int kt = 0; kt < 4; ++kt)
#pragma unroll
            for (int e = 0; e < 8; ++e) {
                uint h_, l_;
                split2u(W2[(32*kt + 8*g + e) * 128 + (16*jt + b)], h_, l_);
                A2[jt][kt][0][e] = (short)(h_ >> 16);
                A2[jt][kt][1][e] = (short)(l_ >> 16);
            }

    // ---- W1^T packed + bias fold: g0,g1 = Wh; g2 = Wl; g3 = [b1h, b1l, 0..] ----
    short8v A1[8];
#pragma unroll
    for (int jt = 0; jt < 8; ++jt)
#pragma unroll
        for (int e = 0; e < 8; ++e) {
            short val;
            if (g == 3) {
                uint h_, l_; split2u(b1[16*jt + b], h_, l_);
                val = (e == 0) ? (short)(h_ >> 16) : (e == 1) ? (short)(l_ >> 16) : (short)0;
            } else {
                uint h_, l_; split2u(W1[e * 128 + 16*jt + b], h_, l_);
                val = (short)(((g == 2) ? l_ : h_) >> 16);
            }
            A1[jt][e] = val;
        }

    // ---- W3^T: A3[kt][lev], rows j' = b (<4 real), k = 32kt + 8g + e ----
    short8v A3[4][2];
#pragma unroll
    for (int kt = 0; kt < 4; ++kt)
#pragma unroll
        for (int e = 0; e < 8; ++e) {
            float x = (b < 4) ? W3[(32*kt + 8*g + e) * 4 + b] : 0.0f;
            uint h_, l_; split2u(x, h_, l_);
            A3[kt][0][e] = (short)(h_ >> 16);
            A3[kt][1][e] = (short)(l_ >> 16);
        }

    f32x4 b3v = *(const f32x4*)b3;

    __syncthreads();   // setup only (single wave; trivial)

    f32x4 h  = {1.0f, 0.0f, 0.0f, 0.0f};
    f32x4 k1 = {0,0,0,0}, k2 = {0,0,0,0}, k3v = {0,0,0,0};
    const float* qp = quat + (size_t)(rowbase + b) * TSTEPS * 4;
    f32x4 qnext = *(const f32x4*)qp;

#pragma unroll 1
    for (int t = 0; t < TSTEPS; ++t) {
        const f32x4 q = qnext;
        const int tn = (t + 1 < TSTEPS) ? t + 1 : t;
        qnext = *(const f32x4*)(qp + 4 * tn);
        uint2 qhi, qlo; split4_pk(q, qhi, qlo);
        f32x4 hnew = {0,0,0,0};

#pragma unroll
        for (int s = 0; s < 4; ++s) {
            f32x4 hs = h;
            if (s == 1)      hs += k1 * (1.0f/3.0f);
            else if (s == 2) hs += k2 - k1 * (1.0f/3.0f);
            else if (s == 3) hs += k1 - k2 + k3v;

            // ---- B0: products g0=WhXh, g1=WhXl, g2=WlXh, g3=bias*1 ----
            uint2 hhi, hlo; split4_pk(hs, hhi, hlo);
            FragU b0;
            if (g == 3)      { b0.u[0] = 0x3F803F80u; b0.u[1] = 0u; b0.u[2] = 0u; b0.u[3] = 0u; }
            else if (g == 1) { b0.u[0] = hlo.x; b0.u[1] = hlo.y; b0.u[2] = qlo.x; b0.u[3] = qlo.y; }
            else             { b0.u[0] = hhi.x; b0.u[1] = hhi.y; b0.u[2] = qhi.x; b0.u[3] = qhi.y; }

            // ---- layer 1 (8 independent MFMAs) + silu + split -> sx1 ----
#pragma unroll
            for (int jt = 0; jt < 8; ++jt) {
                f32x4 z = {0,0,0,0};
                f32x4 c1 = MFMA16(A1[jt], b0.v, z);
                f32x4 sv = silu4(c1);
                uint2 phi, plo; split4_pk(sv, phi, plo);
                const int c  = 4*jt + g;           // chunk = j/4
                const int p  = c >> 1;
                const int hf = (c & 1) * 4;
                *(uint2*)&sx1[SXI(0, p, b) + hf] = phi;
                *(uint2*)&sx1[SXI(1, p, b) + hf] = plo;
            }

            // ---- in-wave gather of all x1 B-frags (k = 32kt + 8g + e) ----
            short8v B2[4][2];
#pragma unroll
            for (int kt = 0; kt < 4; ++kt) {
                B2[kt][0] = *(const short8v*)&sx1[SXI(0, 4*kt + g, b)];
                B2[kt][1] = *(const short8v*)&sx1[SXI(1, 4*kt + g, b)];
            }

            // ---- layer 2: 8 jt x (4 kt x 3 products), dual chains ----
#pragma unroll
            for (int jt = 0; jt < 8; ++jt) {
                f32x4 u = {0,0,0,0}, vv = {0,0,0,0};
#pragma unroll
                for (int kt = 0; kt < 4; ++kt) {
                    if (kt & 1) {
                        vv = MFMA16(A2[jt][kt][1], B2[kt][0], vv);
                        vv = MFMA16(A2[jt][kt][0], B2[kt][1], vv);
                        vv = MFMA16(A2[jt][kt][0], B2[kt][0], vv);
                    } else {
                        u  = MFMA16(A2[jt][kt][1], B2[kt][0], u);
                        u  = MFMA16(A2[jt][kt][0], B2[kt][1], u);
                        u  = MFMA16(A2[jt][kt][0], B2[kt][0], u);
                    }
                }
                f32x4 bb = *(const f32x4*)&sb2s[16*jt + 4*g];
                f32x4 xv = silu4(u + vv + bb);
                uint2 phi, plo; split4_pk(xv, phi, plo);
                const int c  = 4*jt + g;
                const int p  = c >> 1;
                const int hf = (c & 1) * 4;
                *(uint2*)&sx2[SXI(0, p, b) + hf] = phi;
                *(uint2*)&sx2[SXI(1, p, b) + hf] = plo;
            }

            // ---- layer 3: MFMA with W3^T (4-product, exact on split terms) ----
            f32x4 c3a = {0,0,0,0}, c3b = {0,0,0,0};
#pragma unroll
            for (int kt = 0; kt < 4; ++kt) {
                short8v Bh = *(const short8v*)&sx2[SXI(0, 4*kt + g, b)];
                short8v Bl = *(const short8v*)&sx2[SXI(1, 4*kt + g, b)];
                if (kt & 1) {
                    c3b = MFMA16(A3[kt][1], Bl, c3b);
                    c3b = MFMA16(A3[kt][1], Bh, c3b);
                    c3b = MFMA16(A3[kt][0], Bl, c3b);
                    c3b = MFMA16(A3[kt][0], Bh, c3b);
                } else {
                    c3a = MFMA16(A3[kt][1], Bl, c3a);
                    c3a = MFMA16(A3[kt][1], Bh, c3a);
                    c3a = MFMA16(A3[kt][0], Bl, c3a);
                    c3a = MFMA16(A3[kt][0], Bh, c3a);
                }
            }
            f32x4 c3 = c3a + c3b;
            // rows j'=0..3 live in g==0 lanes; in-wave broadcast via LDS
            if (tid < 16) *(f32x4*)&sck[b * 4] = c3;
            f32x4 ks = *(const f32x4*)&sck[b * 4] + b3v;

            const float wgt = (s == 1 || s == 2) ? 0.375f : 0.125f;
            hnew += ks * wgt;
            if (s == 0)      k1  = ks;
            else if (s == 1) k2  = ks;
            else if (s == 2) k3v = ks;
        }
        h += hnew;
    }

    if (tid < 16)
        *(f32x4*)&out[(size_t)(rowbase + b) * 4] = h;
}

extern "C" void kernel_launch(void* const* d_in, const int* in_sizes, int n_in,
                              void* d_out, int out_size, void* d_ws, size_t ws_size,
                              hipStream_t stream)
{
    const float* quat = (const float*)d_in[0];
    const float* W1   = (const float*)d_in[1];
    const float* b1   = (const float*)d_in[2];
    const float* W2   = (const float*)d_in[3];
    const float* b2   = (const float*)d_in[4];
    const float* W3   = (const float*)d_in[5];
    const float* b3   = (const float*)d_in[6];
    float* out        = (float*)d_out;

    const int B = in_sizes[0] / (TSTEPS * 4);   // 16384
    dim3 grid(B / 16), block(64);
    hipLaunchKernelGGL(odernn_v11, grid, block, 0, stream,
                       quat, W1, b1, W2, b2, W3, b3, out);
}

// Round 12
// 6710.738 us; speedup vs baseline: 1.4092x; 1.4092x over previous
//
#include <hip/hip_runtime.h>
#include <hip/hip_bf16.h>

typedef float f32x4  __attribute__((ext_vector_type(4)));
typedef float f32x16 __attribute__((ext_vector_type(16)));
typedef short short8v __attribute__((ext_vector_type(8)));
typedef unsigned int uint;

constexpr int TSTEPS = 512;

union FragU { uint u[4]; short8v v; };

__device__ __forceinline__ float silu_f(float x) {
    return __fdividef(x, 1.0f + __expf(-x));
}

// ---- setup-path split (RNE, bf16 pattern in top 16 bits) ----
__device__ __forceinline__ uint bf16_rne(float x) {
    uint ux = __float_as_uint(x);
    return (ux + 0x7FFFu + ((ux >> 16) & 1u)) & 0xFFFF0000u;
}
__device__ __forceinline__ void split2u(float x, uint &h, uint &l) {
    h = bf16_rne(x);
    float rem = x - __uint_as_float(h);
    l = bf16_rne(rem);
}

// ---- hot-path split via v_cvt_pk_bf16_f32 (bit-identical to split2u) ----
__device__ __forceinline__ uint cvtpk(float a, float b) {
    union { __hip_bfloat162 h; uint u; } cv;
    cv.h = __float22bfloat162_rn(make_float2(a, b));
    return cv.u;
}
__device__ __forceinline__ void split4_pk(const f32x4 v, uint2 &hi, uint2 &lo) {
    hi.x = cvtpk(v.x, v.y);
    hi.y = cvtpk(v.z, v.w);
    float h0 = __uint_as_float(hi.x << 16);
    float h1 = __uint_as_float(hi.x & 0xFFFF0000u);
    float h2 = __uint_as_float(hi.y << 16);
    float h3 = __uint_as_float(hi.y & 0xFFFF0000u);
    lo.x = cvtpk(v.x - h0, v.y - h1);
    lo.y = cvtpk(v.z - h2, v.w - h3);
}

// cross-half (lane^32) sum via v_permlane32_swap_b32 (pure VALU; replaces
// ds_bpermute-based __shfl_xor). Semantics: a'.lo=b.hi, a'.hi=a.hi;
// b'.lo=b.lo, b'.hi=a.lo  => a'+b' = own + partner in ALL lanes.
__device__ __forceinline__ float xhalf_sum(float x) {
    uint a = __float_as_uint(x);
    uint b;
    asm("v_mov_b32 %0, %1\n\t"
        "v_permlane32_swap_b32 %1, %0"
        : "=&v"(b), "+v"(a));
    return __uint_as_float(a) + __uint_as_float(b);
}

// x1 LDS: [kt(8)][gk(2)][lev(2)][b(32)][8 shorts] -> lev planes 512B apart so
// the producer's phi/plo pair is ds_write2_b64-mergeable; consumer reads are
// 16B-stride over b (conflict-free b128).
#define SXI(kt,gk,lev,bb) (((((kt)*2+(gk))*2+(lev))*32+(bb))*8)

// 256 threads / 4 waves / 32 batch rows per block; grid 512 = 2 blocks/CU.
// 32x32x16 MFMA, 2-term RNE split, 3-product L2 (as v10). v13 deltas:
// permlane butterfly (no ds_bpermute), write2-mergeable x1 layout,
// own-partial-in-reg sk3 reduce, setprio around the MFMA cluster.
__global__ __launch_bounds__(256, 2)
void odernn_v13(const float* __restrict__ quat,
                const float* __restrict__ W1, const float* __restrict__ b1,
                const float* __restrict__ W2, const float* __restrict__ b2,
                const float* __restrict__ W3, const float* __restrict__ b3,
                float* __restrict__ out)
{
    __shared__ short sx1[8 * 2 * 2 * 32 * 8];   // 16 KB
    __shared__ float sb1[128];
    __shared__ float sb2[128];
    __shared__ float sk3[4][32][4];             // 2 KB

    const int tid  = threadIdx.x;
    const int w    = tid >> 6;
    const int lane = tid & 63;
    const int b    = lane & 31;    // batch col
    const int gp   = lane >> 5;    // k/lane group
    const int rowbase = blockIdx.x * 32;

    if (tid < 128) { sb1[tid] = b1[tid]; sb2[tid] = b2[tid]; }

    // ---- persistent weight fragments ----
    short8v A2[8][2];   // W2^T: A2[kt][lev][e] = lev(W2[k=16kt+8gp+e][j=32w+b])
#pragma unroll
    for (int kt = 0; kt < 8; ++kt) {
#pragma unroll
        for (int e = 0; e < 8; ++e) {
            float x = W2[(16 * kt + 8 * gp + e) * 128 + (32 * w + b)];
            uint h2_, l2_; split2u(x, h2_, l2_);
            A2[kt][0][e] = (short)(h2_ >> 16);
            A2[kt][1][e] = (short)(l2_ >> 16);
        }
    }
    short8v A1;         // W1^T packed: group0 lanes Wh, group1 lanes Wl
#pragma unroll
    for (int e = 0; e < 8; ++e) {
        float x = W1[e * 128 + (32 * w + b)];
        uint h1_, l1_; split2u(x, h1_, l1_);
        A1[e] = (short)((gp ? l1_ : h1_) >> 16);
    }
    // per-lane j-slice of W3 in registers: i -> j = 32w + 8*(i>>2) + (i&3) + 4gp
    f32x4 W3r[16];
#pragma unroll
    for (int i = 0; i < 16; ++i) {
        const int j = 32 * w + 8 * (i >> 2) + (i & 3) + 4 * gp;
        W3r[i] = *(const f32x4*)&W3[j * 4];
    }
    f32x4 b3v = *(const f32x4*)b3;

    __syncthreads();

    f32x4 h  = {1.0f, 0, 0, 0};
    f32x4 k1 = {0,0,0,0}, k2 = {0,0,0,0}, k3v = {0,0,0,0};
    const float* qp = quat + (size_t)(rowbase + b) * TSTEPS * 4;

    f32x4 qnext = *(const f32x4*)qp;    // double-buffered q

#pragma unroll 1
    for (int t = 0; t < TSTEPS; ++t) {
        const f32x4 q = qnext;
        const int tn = (t + 1 < TSTEPS) ? t + 1 : t;
        qnext = *(const f32x4*)(qp + 4 * tn);   // prefetch next t

        uint2 qhi, qlo;
        split4_pk(q, qhi, qlo);
        f32x4 hnew = {0,0,0,0};

#pragma unroll
        for (int s = 0; s < 4; ++s) {
            f32x4 hs = h;
            if (s == 1)      hs += k1 * (1.0f/3.0f);
            else if (s == 2) hs += k2 - k1 * (1.0f/3.0f);
            else if (s == 3) hs += k1 - k2 + k3v;

            // ---- B0 pair: own-level and swapped-level ----
            uint2 hhi, hlo;
            split4_pk(hs, hhi, hlo);
            FragU b0a, b0b;
            b0a.u[0] = gp ? hlo.x : hhi.x;  b0a.u[1] = gp ? hlo.y : hhi.y;
            b0a.u[2] = gp ? qlo.x : qhi.x;  b0a.u[3] = gp ? qlo.y : qhi.y;
            b0b.u[0] = gp ? hhi.x : hlo.x;  b0b.u[1] = gp ? hhi.y : hlo.y;
            b0b.u[2] = gp ? qhi.x : qlo.x;  b0b.u[3] = gp ? qhi.y : qlo.y;

            // ---- layer 1: 2 MFMAs give all 4 level products ----
            f32x16 c1;
#pragma unroll
            for (int qd = 0; qd < 4; ++qd) {
                f32x4 bv = *(const f32x4*)&sb1[32 * w + 8 * qd + 4 * gp];
                c1[4*qd+0] = bv.x; c1[4*qd+1] = bv.y;
                c1[4*qd+2] = bv.z; c1[4*qd+3] = bv.w;
            }
            c1 = __builtin_amdgcn_mfma_f32_32x32x16_bf16(A1, b0a.v, c1, 0, 0, 0);
            c1 = __builtin_amdgcn_mfma_f32_32x32x16_bf16(A1, b0b.v, c1, 0, 0, 0);

            // ---- silu + producer split -> LDS (write2-mergeable pair) ----
#pragma unroll
            for (int qd = 0; qd < 4; ++qd) {
                f32x4 sv;
                sv.x = silu_f(c1[4*qd+0]); sv.y = silu_f(c1[4*qd+1]);
                sv.z = silu_f(c1[4*qd+2]); sv.w = silu_f(c1[4*qd+3]);
                uint2 phi, plo;
                split4_pk(sv, phi, plo);
                const int kt = 2 * w + (qd >> 1);
                const int gk = qd & 1;
                const int base = SXI(kt, gk, 0, b) + 4 * gp;
                *(uint2*)&sx1[base]       = phi;        // lev 0
                *(uint2*)&sx1[base + 256] = plo;        // lev 1 (+512B)
            }
            __syncthreads();

            // ---- layer 2: full K=128, 3-product split MFMA per ktile ----
            f32x16 u, vv;
#pragma unroll
            for (int qd = 0; qd < 4; ++qd) {
                f32x4 bv = *(const f32x4*)&sb2[32 * w + 8 * qd + 4 * gp];
                u[4*qd+0] = bv.x; u[4*qd+1] = bv.y;
                u[4*qd+2] = bv.z; u[4*qd+3] = bv.w;
            }
#pragma unroll
            for (int i = 0; i < 16; ++i) vv[i] = 0.0f;

            __builtin_amdgcn_s_setprio(1);
#pragma unroll
            for (int kt = 0; kt < 8; ++kt) {
                short8v Bh = *(const short8v*)&sx1[SXI(kt, gp, 0, b)];
                short8v Bl = *(const short8v*)&sx1[SXI(kt, gp, 1, b)];
                if (kt & 1) {
                    vv = __builtin_amdgcn_mfma_f32_32x32x16_bf16(A2[kt][1], Bh, vv, 0, 0, 0);
                    vv = __builtin_amdgcn_mfma_f32_32x32x16_bf16(A2[kt][0], Bl, vv, 0, 0, 0);
                    vv = __builtin_amdgcn_mfma_f32_32x32x16_bf16(A2[kt][0], Bh, vv, 0, 0, 0);
                } else {
                    u = __builtin_amdgcn_mfma_f32_32x32x16_bf16(A2[kt][1], Bh, u, 0, 0, 0);
                    u = __builtin_amdgcn_mfma_f32_32x32x16_bf16(A2[kt][0], Bl, u, 0, 0, 0);
                    u = __builtin_amdgcn_mfma_f32_32x32x16_bf16(A2[kt][0], Bh, u, 0, 0, 0);
                }
            }
            __builtin_amdgcn_s_setprio(0);

            // ---- layer 3: fp32 dot with register-resident W3 rows ----
            f32x4 p = {0.0f, 0.0f, 0.0f, 0.0f};
#pragma unroll
            for (int i = 0; i < 16; ++i) {
                const float xv = silu_f(u[i] + vv[i]);
                p += xv * W3r[i];
            }
            // cross-half reduce via permlane (VALU) -> all lanes hold wave partial
            p.x = xhalf_sum(p.x);
            p.y = xhalf_sum(p.y);
            p.z = xhalf_sum(p.z);
            p.w = xhalf_sum(p.w);
            if (lane < 32) *(f32x4*)&sk3[w][lane][0] = p;
            __syncthreads();

            // own partial stays in-reg; read only the 3 other waves
            f32x4 ks = b3v + p;
#pragma unroll
            for (int i = 1; i < 4; ++i)
                ks += *(const f32x4*)&sk3[(w + i) & 3][b][0];

            const float wgt = (s == 1 || s == 2) ? 0.375f : 0.125f;
            hnew += ks * wgt;
            if (s == 0)      k1  = ks;
            else if (s == 1) k2  = ks;
            else if (s == 2) k3v = ks;
        }
        h += hnew;
    }

    if (tid < 32)
        *(f32x4*)&out[(size_t)(rowbase + tid) * 4] = h;
}

extern "C" void kernel_launch(void* const* d_in, const int* in_sizes, int n_in,
                              void* d_out, int out_size, void* d_ws, size_t ws_size,
                              hipStream_t stream)
{
    const float* quat = (const float*)d_in[0];
    const float* W1   = (const float*)d_in[1];
    const float* b1   = (const float*)d_in[2];
    const float* W2   = (const float*)d_in[3];
    const float* b2   = (const float*)d_in[4];
    const float* W3   = (const float*)d_in[5];
    const float* b3   = (const float*)d_in[6];
    float* out        = (float*)d_out;

    const int B = in_sizes[0] / (TSTEPS * 4);   // 16384
    dim3 grid(B / 32), block(256);
    hipLaunchKernelGGL(odernn_v13, grid, block, 0, stream,
                       quat, W1, b1, W2, b2, W3, b3, out);
}

// Round 15
// 6681.535 us; speedup vs baseline: 1.4154x; 1.0044x over previous
//
#include <hip/hip_runtime.h>
#include <hip/hip_bf16.h>

typedef float f32x4  __attribute__((ext_vector_type(4)));
typedef float f32x16 __attribute__((ext_vector_type(16)));
typedef short short8v __attribute__((ext_vector_type(8)));
typedef unsigned int uint;

constexpr int TSTEPS = 512;

union FragU { uint u[4]; short8v v; };

__device__ __forceinline__ float silu_f(float x) {
    return __fdividef(x, 1.0f + __expf(-x));
}

// ---- setup-path split (RNE, bf16 pattern in top 16 bits) ----
__device__ __forceinline__ uint bf16_rne(float x) {
    uint ux = __float_as_uint(x);
    return (ux + 0x7FFFu + ((ux >> 16) & 1u)) & 0xFFFF0000u;
}
__device__ __forceinline__ void split2u(float x, uint &h, uint &l) {
    h = bf16_rne(x);
    float rem = x - __uint_as_float(h);
    l = bf16_rne(rem);
}

// ---- hot-path split via v_cvt_pk_bf16_f32 (bit-identical to split2u) ----
__device__ __forceinline__ uint cvtpk(float a, float b) {
    union { __hip_bfloat162 h; uint u; } cv;
    cv.h = __float22bfloat162_rn(make_float2(a, b));
    return cv.u;
}
__device__ __forceinline__ void split4_pk(const f32x4 v, uint2 &hi, uint2 &lo) {
    hi.x = cvtpk(v.x, v.y);
    hi.y = cvtpk(v.z, v.w);
    float h0 = __uint_as_float(hi.x << 16);
    float h1 = __uint_as_float(hi.x & 0xFFFF0000u);
    float h2 = __uint_as_float(hi.y << 16);
    float h3 = __uint_as_float(hi.y & 0xFFFF0000u);
    lo.x = cvtpk(v.x - h0, v.y - h1);
    lo.y = cvtpk(v.z - h2, v.w - h3);
}

// cross-half (lane^32) sum via v_permlane32_swap_b32 (pure VALU, proven v13)
__device__ __forceinline__ float xhalf_sum(float x) {
    uint a = __float_as_uint(x);
    uint b;
    asm("v_mov_b32 %0, %1\n\t"
        "v_permlane32_swap_b32 %1, %0"
        : "=&v"(b), "+v"(a));
    return __uint_as_float(a) + __uint_as_float(b);
}

// x1 LDS: [kt(8)][gk(2)][lev(2)][b(32)][8 shorts]
#define SXI(kt,gk,lev,bb) (((((kt)*2+(gk))*2+(lev))*32+(bb))*8)

// 256 threads / 4 waves / 32 batch rows per block; grid 512 = 2 blocks/CU.
// 32x32x16 MFMA, 2-term RNE split, 3-product L2 (v13 structure).
// v16 delta vs v13: b1/b2 biases in registers (-8 DS ops/wave-stage).
__global__ __launch_bounds__(256, 2)
void odernn_v16(const float* __restrict__ quat,
                const float* __restrict__ W1, const float* __restrict__ b1,
                const float* __restrict__ W2, const float* __restrict__ b2,
                const float* __restrict__ W3, const float* __restrict__ b3,
                float* __restrict__ out)
{
    __shared__ short sx1[8 * 2 * 2 * 32 * 8];   // 16 KB
    __shared__ float sk3[4][32][4];             // 2 KB

    const int tid  = threadIdx.x;
    const int w    = tid >> 6;
    const int lane = tid & 63;
    const int b    = lane & 31;    // batch col
    const int gp   = lane >> 5;    // k/lane group
    const int rowbase = blockIdx.x * 32;

    // ---- persistent weight fragments ----
    short8v A2[8][2];   // W2^T: A2[kt][lev][e] = lev(W2[k=16kt+8gp+e][j=32w+b])
#pragma unroll
    for (int kt = 0; kt < 8; ++kt) {
#pragma unroll
        for (int e = 0; e < 8; ++e) {
            float x = W2[(16 * kt + 8 * gp + e) * 128 + (32 * w + b)];
            uint h2_, l2_; split2u(x, h2_, l2_);
            A2[kt][0][e] = (short)(h2_ >> 16);
            A2[kt][1][e] = (short)(l2_ >> 16);
        }
    }
    short8v A1;         // W1^T packed: group0 lanes Wh, group1 lanes Wl
#pragma unroll
    for (int e = 0; e < 8; ++e) {
        float x = W1[e * 128 + (32 * w + b)];
        uint h1_, l1_; split2u(x, h1_, l1_);
        A1[e] = (short)((gp ? l1_ : h1_) >> 16);
    }
    // per-lane j-slice of W3: i -> j = 32w + 8*(i>>2) + (i&3) + 4gp
    f32x4 W3r[16];
#pragma unroll
    for (int i = 0; i < 16; ++i) {
        const int j = 32 * w + 8 * (i >> 2) + (i & 3) + 4 * gp;
        W3r[i] = *(const f32x4*)&W3[j * 4];
    }
    // biases in registers (c1/c2 init slices, same values as v13's sb1/sb2 reads)
    f32x4 b1r[4], b2r[4];
#pragma unroll
    for (int qd = 0; qd < 4; ++qd) {
        b1r[qd] = *(const f32x4*)&b1[32 * w + 8 * qd + 4 * gp];
        b2r[qd] = *(const f32x4*)&b2[32 * w + 8 * qd + 4 * gp];
    }
    f32x4 b3v = *(const f32x4*)b3;

    __syncthreads();

    f32x4 h  = {1.0f, 0, 0, 0};
    f32x4 k1 = {0,0,0,0}, k2 = {0,0,0,0}, k3v = {0,0,0,0};
    const float* qp = quat + (size_t)(rowbase + b) * TSTEPS * 4;

    f32x4 qnext = *(const f32x4*)qp;    // double-buffered q

#pragma unroll 1
    for (int t = 0; t < TSTEPS; ++t) {
        const f32x4 q = qnext;
        const int tn = (t + 1 < TSTEPS) ? t + 1 : t;
        qnext = *(const f32x4*)(qp + 4 * tn);   // prefetch next t

        uint2 qhi, qlo;
        split4_pk(q, qhi, qlo);
        f32x4 hnew = {0,0,0,0};

#pragma unroll
        for (int s = 0; s < 4; ++s) {
            f32x4 hs = h;
            if (s == 1)      hs += k1 * (1.0f/3.0f);
            else if (s == 2) hs += k2 - k1 * (1.0f/3.0f);
            else if (s == 3) hs += k1 - k2 + k3v;

            // ---- B0 pair: own-level and swapped-level ----
            uint2 hhi, hlo;
            split4_pk(hs, hhi, hlo);
            FragU b0a, b0b;
            b0a.u[0] = gp ? hlo.x : hhi.x;  b0a.u[1] = gp ? hlo.y : hhi.y;
            b0a.u[2] = gp ? qlo.x : qhi.x;  b0a.u[3] = gp ? qlo.y : qhi.y;
            b0b.u[0] = gp ? hhi.x : hlo.x;  b0b.u[1] = gp ? hhi.y : hlo.y;
            b0b.u[2] = gp ? qhi.x : qlo.x;  b0b.u[3] = gp ? qhi.y : qlo.y;

            // ---- layer 1: 2 MFMAs give all 4 level products ----
            f32x16 c1;
#pragma unroll
            for (int qd = 0; qd < 4; ++qd) {
                c1[4*qd+0] = b1r[qd].x; c1[4*qd+1] = b1r[qd].y;
                c1[4*qd+2] = b1r[qd].z; c1[4*qd+3] = b1r[qd].w;
            }
            c1 = __builtin_amdgcn_mfma_f32_32x32x16_bf16(A1, b0a.v, c1, 0, 0, 0);
            c1 = __builtin_amdgcn_mfma_f32_32x32x16_bf16(A1, b0b.v, c1, 0, 0, 0);

            // ---- silu + producer split -> LDS ----
#pragma unroll
            for (int qd = 0; qd < 4; ++qd) {
                f32x4 sv;
                sv.x = silu_f(c1[4*qd+0]); sv.y = silu_f(c1[4*qd+1]);
                sv.z = silu_f(c1[4*qd+2]); sv.w = silu_f(c1[4*qd+3]);
                uint2 phi, plo;
                split4_pk(sv, phi, plo);
                const int kt = 2 * w + (qd >> 1);
                const int gk = qd & 1;
                const int base = SXI(kt, gk, 0, b) + 4 * gp;
                *(uint2*)&sx1[base]       = phi;        // lev 0
                *(uint2*)&sx1[base + 256] = plo;        // lev 1 (+512B)
            }
            __syncthreads();

            // ---- layer 2: full K=128, 3-product split MFMA per ktile ----
            f32x16 u, vv;
#pragma unroll
            for (int qd = 0; qd < 4; ++qd) {
                u[4*qd+0] = b2r[qd].x; u[4*qd+1] = b2r[qd].y;
                u[4*qd+2] = b2r[qd].z; u[4*qd+3] = b2r[qd].w;
            }
#pragma unroll
            for (int i = 0; i < 16; ++i) vv[i] = 0.0f;

            __builtin_amdgcn_s_setprio(1);
#pragma unroll
            for (int kt = 0; kt < 8; ++kt) {
                short8v Bh = *(const short8v*)&sx1[SXI(kt, gp, 0, b)];
                short8v Bl = *(const short8v*)&sx1[SXI(kt, gp, 1, b)];
                if (kt & 1) {
                    vv = __builtin_amdgcn_mfma_f32_32x32x16_bf16(A2[kt][1], Bh, vv, 0, 0, 0);
                    vv = __builtin_amdgcn_mfma_f32_32x32x16_bf16(A2[kt][0], Bl, vv, 0, 0, 0);
                    vv = __builtin_amdgcn_mfma_f32_32x32x16_bf16(A2[kt][0], Bh, vv, 0, 0, 0);
                } else {
                    u = __builtin_amdgcn_mfma_f32_32x32x16_bf16(A2[kt][1], Bh, u, 0, 0, 0);
                    u = __builtin_amdgcn_mfma_f32_32x32x16_bf16(A2[kt][0], Bl, u, 0, 0, 0);
                    u = __builtin_amdgcn_mfma_f32_32x32x16_bf16(A2[kt][0], Bh, u, 0, 0, 0);
                }
            }
            __builtin_amdgcn_s_setprio(0);

            // ---- layer 3: fp32 dot with register-resident W3 rows ----
            f32x4 p = {0.0f, 0.0f, 0.0f, 0.0f};
#pragma unroll
            for (int i = 0; i < 16; ++i) {
                const float xv = silu_f(u[i] + vv[i]);
                p += xv * W3r[i];
            }
            // cross-half reduce via permlane -> all lanes hold wave partial
            p.x = xhalf_sum(p.x);
            p.y = xhalf_sum(p.y);
            p.z = xhalf_sum(p.z);
            p.w = xhalf_sum(p.w);
            if (lane < 32) *(f32x4*)&sk3[w][lane][0] = p;
            __syncthreads();

            // own partial in-reg; read only the 3 other waves
            f32x4 ks = b3v + p;
#pragma unroll
            for (int i = 1; i < 4; ++i)
                ks += *(const f32x4*)&sk3[(w + i) & 3][b][0];

            const float wgt = (s == 1 || s == 2) ? 0.375f : 0.125f;
            hnew += ks * wgt;
            if (s == 0)      k1  = ks;
            else if (s == 1) k2  = ks;
            else if (s == 2) k3v = ks;
        }
        h += hnew;
    }

    if (tid < 32)
        *(f32x4*)&out[(size_t)(rowbase + tid) * 4] = h;
}

extern "C" void kernel_launch(void* const* d_in, const int* in_sizes, int n_in,
                              void* d_out, int out_size, void* d_ws, size_t ws_size,
                              hipStream_t stream)
{
    const float* quat = (const float*)d_in[0];
    const float* W1   = (const float*)d_in[1];
    const float* b1   = (const float*)d_in[2];
    const float* W2   = (const float*)d_in[3];
    const float* b2   = (const float*)d_in[4];
    const float* W3   = (const float*)d_in[5];
    const float* b3   = (const float*)d_in[6];
    float* out        = (float*)d_out;

    const int B = in_sizes[0] / (TSTEPS * 4);   // 16384
    dim3 grid(B / 32), block(256);
    hipLaunchKernelGGL(odernn_v16, grid, block, 0, stream,
                       quat, W1, b1, W2, b2, W3, b3, out);
}